// Round 1
// baseline (1063.595 us; speedup 1.0000x reference)
//
#include <hip/hip_runtime.h>
#include <hip/hip_bf16.h>
#include <cstdint>
#include <cstddef>

// Problem constants
#define B_ 64
#define S_ 512
#define E_ 1024
#define H_ 16
#define D_ 64

typedef __attribute__((ext_vector_type(8))) short s8v;   // 8 bf16 = 4 VGPRs (A/B frag)
typedef __attribute__((ext_vector_type(4))) float f4v;   // C/D frag

__device__ __forceinline__ ushort f2bf(float f) {
  uint32_t u = __builtin_bit_cast(uint32_t, f);
  u += 0x7fffu + ((u >> 16) & 1u);   // RNE
  return (ushort)(u >> 16);
}

// async global->LDS, 16B per lane. LDS dest must be wave-uniform base + lane*16.
__device__ __forceinline__ void async_cp16(const void* g, void* l) {
  __builtin_amdgcn_global_load_lds(
      (const __attribute__((address_space(1))) unsigned int*)g,
      (__attribute__((address_space(3))) unsigned int*)(uintptr_t)l,
      16, 0, 0);
}

// ---------------- fp32 -> bf16 convert (X) ----------------
__global__ __launch_bounds__(256) void convertx(const float* __restrict__ X,
                                                ushort* __restrict__ Y) {
  size_t i = ((size_t)blockIdx.x * 256 + threadIdx.x) * 4;
  float4 v = *(const float4*)(X + i);
  uint2 p;
  p.x = (uint32_t)f2bf(v.x) | ((uint32_t)f2bf(v.y) << 16);
  p.y = (uint32_t)f2bf(v.z) | ((uint32_t)f2bf(v.w) << 16);
  *(uint2*)(Y + i) = p;
}

// ---------------- W (ExE fp32) -> Wt (ExE bf16, transposed) ----------------
__global__ __launch_bounds__(256) void transpose_w(const float* __restrict__ W,
                                                   ushort* __restrict__ Wt) {
  __shared__ ushort T[32][33];
  int x = threadIdx.x & 31, y = threadIdx.x >> 5;  // 32 x 8
  int c0 = blockIdx.x * 32;  // col base (n)
  int r0 = blockIdx.y * 32;  // row base (k)
#pragma unroll
  for (int i = 0; i < 4; i++) {
    int r = y + i * 8;
    T[x][r] = f2bf(W[(size_t)(r0 + r) * E_ + c0 + x]);  // coalesced read
  }
  __syncthreads();
#pragma unroll
  for (int i = 0; i < 4; i++) {
    int r = y + i * 8;
    Wt[(size_t)(c0 + r) * E_ + r0 + x] = T[r][x];  // coalesced write
  }
}

// ---------------- bf16 GEMM: C[M,N] = A[M,K] * Bt[N,K]^T ----------------
// mode 0: bf16 out, scattered to [B,H,S,D] (split heads) from (m=b*S+s, n=h*64+d)
// mode 1: fp32 out row-major + bias[n]
__global__ __launch_bounds__(256) void gemm_bt_kernel(
    const ushort* __restrict__ A, const ushort* __restrict__ Bt,
    void* __restrict__ Cv, const float* __restrict__ bias,
    int M, int N, int K, int mode) {
  __shared__ ushort As[128 * 64];
  __shared__ ushort Bs[128 * 64];
  const int tid = threadIdx.x;
  const int m0 = blockIdx.x * 128;
  const int n0 = blockIdx.y * 128;
  const int wave = tid >> 6, lane = tid & 63;
  const int wm = (wave >> 1) * 64, wn = (wave & 1) * 64;
  const int lrow = lane & 15, quad = lane >> 4;

  f4v acc[4][4];
#pragma unroll
  for (int i = 0; i < 4; i++)
#pragma unroll
    for (int j = 0; j < 4; j++) acc[i][j] = (f4v){0.f, 0.f, 0.f, 0.f};

  for (int k0 = 0; k0 < K; k0 += 64) {
    __syncthreads();
#pragma unroll
    for (int i = 0; i < 4; i++) {
      int c = i * 256 + tid;
      int r = c >> 3, cc = c & 7;
      async_cp16(A + (size_t)(m0 + r) * K + k0 + cc * 8, (void*)&As[c * 8]);
    }
#pragma unroll
    for (int i = 0; i < 4; i++) {
      int c = i * 256 + tid;
      int r = c >> 3, cc = c & 7;
      async_cp16(Bt + (size_t)(n0 + r) * K + k0 + cc * 8, (void*)&Bs[c * 8]);
    }
    __syncthreads();
#pragma unroll
    for (int kk = 0; kk < 2; kk++) {
      s8v a[4], b[4];
#pragma unroll
      for (int mi = 0; mi < 4; mi++)
        a[mi] = *(const s8v*)&As[(wm + mi * 16 + lrow) * 64 + kk * 32 + quad * 8];
#pragma unroll
      for (int ni = 0; ni < 4; ni++)
        b[ni] = *(const s8v*)&Bs[(wn + ni * 16 + lrow) * 64 + kk * 32 + quad * 8];
#pragma unroll
      for (int mi = 0; mi < 4; mi++)
#pragma unroll
        for (int ni = 0; ni < 4; ni++)
          acc[mi][ni] = __builtin_amdgcn_mfma_f32_16x16x32_bf16(a[mi], b[ni], acc[mi][ni], 0, 0, 0);
    }
  }

  if (mode == 0) {
    // C/D layout: col = lane&15, row = quad*4 + reg
    ushort* C = (ushort*)Cv;
#pragma unroll
    for (int mi = 0; mi < 4; mi++)
#pragma unroll
      for (int ni = 0; ni < 4; ni++) {
        int n = n0 + wn + ni * 16 + lrow;
        int h = n >> 6, d = n & 63;
#pragma unroll
        for (int r = 0; r < 4; r++) {
          int m = m0 + wm + mi * 16 + quad * 4 + r;
          int bb = m >> 9, s = m & 511;
          C[(((size_t)bb * H_ + h) * S_ + s) * D_ + d] = f2bf(acc[mi][ni][r]);
        }
      }
  } else {
    float* C = (float*)Cv;
#pragma unroll
    for (int mi = 0; mi < 4; mi++)
#pragma unroll
      for (int ni = 0; ni < 4; ni++) {
        int n = n0 + wn + ni * 16 + lrow;
        float bv = bias[n];
#pragma unroll
        for (int r = 0; r < 4; r++) {
          int m = m0 + wm + mi * 16 + quad * 4 + r;
          C[(size_t)m * N + n] = acc[mi][ni][r] + bv;
        }
      }
  }
}

// ---------------- fused causal flash attention ----------------
// grid: (S/64, B*H). block: 256 (4 waves). Wave w owns q rows qb*64+w*16 .. +15.
__global__ __launch_bounds__(256) void attn_kernel(
    const ushort* __restrict__ Qg, const ushort* __restrict__ Kg,
    const ushort* __restrict__ Vg, ushort* __restrict__ AO) {
  __shared__ ushort Qs[64 * 64];
  __shared__ ushort Ks[64 * 64];
  __shared__ ushort Vts[64 * 64];       // V tile transposed: [d][s_local]
  __shared__ ushort Ps[4][16 * 72];     // per-wave P / O staging, stride 72 (pad)

  const int qb = blockIdx.x;            // 0..7
  const int bh = blockIdx.y;            // 0..1023
  const int b = bh >> 4, h = bh & 15;
  const int tid = threadIdx.x, wave = tid >> 6, lane = tid & 63;
  const int lrow = lane & 15, quad = lane >> 4;
  const size_t base = (size_t)bh * (S_ * D_);

  // stage Q tile (64x64)
#pragma unroll
  for (int i = 0; i < 2; i++) {
    int c = i * 256 + tid;
    int r = c >> 3, cc = c & 7;
    async_cp16(Qg + base + (size_t)(qb * 64 + r) * 64 + cc * 8, (void*)&Qs[c * 8]);
  }
  __syncthreads();
  s8v qf[2];
#pragma unroll
  for (int kk = 0; kk < 2; kk++)
    qf[kk] = *(const s8v*)&Qs[(wave * 16 + lrow) * 64 + kk * 32 + quad * 8];

  f4v o[4];
#pragma unroll
  for (int i = 0; i < 4; i++) o[i] = (f4v){0.f, 0.f, 0.f, 0.f};
  float mr[4], lr[4];
#pragma unroll
  for (int r = 0; r < 4; r++) { mr[r] = -INFINITY; lr[r] = 0.f; }

  ushort* pw = &Ps[wave][0];

  for (int kt = 0; kt <= qb; kt++) {
    __syncthreads();  // previous iter's Ks/Vts reads done
    // stage K tile (64x64) direct to LDS
#pragma unroll
    for (int i = 0; i < 2; i++) {
      int c = i * 256 + tid;
      int r = c >> 3, cc = c & 7;
      async_cp16(Kg + base + (size_t)(kt * 64 + r) * 64 + cc * 8, (void*)&Ks[c * 8]);
    }
    // stage V tile transposed into Vts[d][sl]
#pragma unroll
    for (int i = 0; i < 2; i++) {
      int c = i * 256 + tid;
      int sl = c >> 3, dc = c & 7;
      uint4 vv = *(const uint4*)(Vg + base + (size_t)(kt * 64 + sl) * 64 + dc * 8);
      const ushort* ev = (const ushort*)&vv;
#pragma unroll
      for (int j = 0; j < 8; j++) Vts[(dc * 8 + j) * 64 + sl] = ev[j];
    }
    __syncthreads();

    // scores: 16 q-rows x 64 k-cols per wave
    f4v sc[4];
#pragma unroll
    for (int i = 0; i < 4; i++) sc[i] = (f4v){0.f, 0.f, 0.f, 0.f};
#pragma unroll
    for (int kk = 0; kk < 2; kk++)
#pragma unroll
      for (int ni = 0; ni < 4; ni++) {
        s8v kf = *(const s8v*)&Ks[(ni * 16 + lrow) * 64 + kk * 32 + quad * 8];
        sc[ni] = __builtin_amdgcn_mfma_f32_16x16x32_bf16(qf[kk], kf, sc[ni], 0, 0, 0);
      }

    // causal mask (only the diagonal tile needs it)
    const int qrow0 = qb * 64 + wave * 16 + quad * 4;
    if (kt == qb) {
#pragma unroll
      for (int ni = 0; ni < 4; ni++) {
        int kcol = kt * 64 + ni * 16 + lrow;
#pragma unroll
        for (int r = 0; r < 4; r++)
          if (kcol > qrow0 + r) sc[ni][r] = -INFINITY;
      }
    }

    // online softmax: block row max (across 4 tiles, then 16 lanes of quad)
    float bm[4];
#pragma unroll
    for (int r = 0; r < 4; r++)
      bm[r] = fmaxf(fmaxf(sc[0][r], sc[1][r]), fmaxf(sc[2][r], sc[3][r]));
#pragma unroll
    for (int off = 1; off < 16; off <<= 1)
#pragma unroll
      for (int r = 0; r < 4; r++) bm[r] = fmaxf(bm[r], __shfl_xor(bm[r], off));

    float al[4];
#pragma unroll
    for (int r = 0; r < 4; r++) {
      float mn = fmaxf(mr[r], bm[r]);
      al[r] = __expf(mr[r] - mn);
      mr[r] = mn;
    }
    float bs[4] = {0.f, 0.f, 0.f, 0.f};
#pragma unroll
    for (int ni = 0; ni < 4; ni++)
#pragma unroll
      for (int r = 0; r < 4; r++) {
        float p = __expf(sc[ni][r] - mr[r]);
        sc[ni][r] = p;
        bs[r] += p;
      }
#pragma unroll
    for (int off = 1; off < 16; off <<= 1)
#pragma unroll
      for (int r = 0; r < 4; r++) bs[r] += __shfl_xor(bs[r], off);
#pragma unroll
    for (int r = 0; r < 4; r++) lr[r] = lr[r] * al[r] + bs[r];
#pragma unroll
    for (int di = 0; di < 4; di++)
#pragma unroll
      for (int r = 0; r < 4; r++) o[di][r] *= al[r];

    // P (C-layout) -> LDS (row-major, stride 72) -> A-layout frags. Wave-local.
#pragma unroll
    for (int ni = 0; ni < 4; ni++)
#pragma unroll
      for (int r = 0; r < 4; r++)
        pw[(quad * 4 + r) * 72 + ni * 16 + lrow] = f2bf(sc[ni][r]);

#pragma unroll
    for (int kk = 0; kk < 2; kk++) {
      s8v pf = *(const s8v*)&pw[lrow * 72 + kk * 32 + quad * 8];
#pragma unroll
      for (int di = 0; di < 4; di++) {
        s8v vf = *(const s8v*)&Vts[(di * 16 + lrow) * 64 + kk * 32 + quad * 8];
        o[di] = __builtin_amdgcn_mfma_f32_16x16x32_bf16(pf, vf, o[di], 0, 0, 0);
      }
    }
  }

  // normalize and write AO[b][s][h*64+d] (merged heads) via LDS for coalescing
  float inv[4];
#pragma unroll
  for (int r = 0; r < 4; r++) inv[r] = 1.0f / lr[r];
#pragma unroll
  for (int di = 0; di < 4; di++)
#pragma unroll
    for (int r = 0; r < 4; r++)
      pw[(quad * 4 + r) * 72 + di * 16 + lrow] = f2bf(o[di][r] * inv[r]);

#pragma unroll
  for (int i = 0; i < 2; i++) {
    int c = i * 64 + lane;
    int row = c >> 3, cc = c & 7;
    uint4 val = *(const uint4*)&pw[row * 72 + cc * 8];
    int q = qb * 64 + wave * 16 + row;
    size_t off = ((size_t)b * S_ + q) * E_ + h * 64 + cc * 8;
    *(uint4*)&AO[off] = val;
  }
}

// ---------------- launch ----------------
extern "C" void kernel_launch(void* const* d_in, const int* in_sizes, int n_in,
                              void* d_out, int out_size, void* d_ws, size_t ws_size,
                              hipStream_t stream) {
  const float* X = (const float*)d_in[0];
  const float* Wq = (const float*)d_in[1];
  const float* Wk = (const float*)d_in[2];
  const float* Wv = (const float*)d_in[3];
  const float* Wo = (const float*)d_in[4];
  const float* bo = (const float*)d_in[5];
  float* out = (float*)d_out;

  // ws layout (bytes). AO aliases Xb (Xb dead after V projection). Total ~277 MB.
  char* ws = (char*)d_ws;
  ushort* Xb = (ushort*)(ws);                      //  67,108,864
  ushort* Wqt = (ushort*)(ws + 67108864);          //   2,097,152
  ushort* Wkt = (ushort*)(ws + 69206016);
  ushort* Wvt = (ushort*)(ws + 71303168);
  ushort* Wot = (ushort*)(ws + 73400320);
  ushort* Qb = (ushort*)(ws + 75497472);           //  67,108,864
  ushort* Kb = (ushort*)(ws + 142606336);          //  67,108,864
  ushort* Vb = (ushort*)(ws + 209715200);          //  67,108,864  (end 276,824,064)
  ushort* AO = Xb;

  convertx<<<32768, 256, 0, stream>>>(X, Xb);
  transpose_w<<<dim3(32, 32), 256, 0, stream>>>(Wq, Wqt);
  transpose_w<<<dim3(32, 32), 256, 0, stream>>>(Wk, Wkt);
  transpose_w<<<dim3(32, 32), 256, 0, stream>>>(Wv, Wvt);
  transpose_w<<<dim3(32, 32), 256, 0, stream>>>(Wo, Wot);

  gemm_bt_kernel<<<dim3(256, 8), 256, 0, stream>>>(Xb, Wqt, Qb, nullptr,
                                                   B_ * S_, E_, E_, 0);
  gemm_bt_kernel<<<dim3(256, 8), 256, 0, stream>>>(Xb, Wkt, Kb, nullptr,
                                                   B_ * S_, E_, E_, 0);
  gemm_bt_kernel<<<dim3(256, 8), 256, 0, stream>>>(Xb, Wvt, Vb, nullptr,
                                                   B_ * S_, E_, E_, 0);

  attn_kernel<<<dim3(8, 1024), 256, 0, stream>>>(Qb, Kb, Vb, AO);

  gemm_bt_kernel<<<dim3(256, 8), 256, 0, stream>>>(AO, Wot, out, bo,
                                                   B_ * S_, E_, E_, 1);
}

// Round 2
// 927.993 us; speedup vs baseline: 1.1461x; 1.1461x over previous
//
#include <hip/hip_runtime.h>
#include <hip/hip_bf16.h>
#include <cstdint>
#include <cstddef>

// Problem constants
#define B_ 64
#define S_ 512
#define E_ 1024
#define H_ 16
#define D_ 64

typedef __attribute__((ext_vector_type(8))) short s8v;   // 8 bf16 = 4 VGPRs (A/B frag)
typedef __attribute__((ext_vector_type(4))) float f4v;   // C/D frag

__device__ __forceinline__ ushort f2bf(float f) {
  uint32_t u = __builtin_bit_cast(uint32_t, f);
  u += 0x7fffu + ((u >> 16) & 1u);   // RNE
  return (ushort)(u >> 16);
}

// async global->LDS, 16B per lane. LDS dest must be wave-uniform base + lane*16.
__device__ __forceinline__ void async_cp16(const void* g, void* l) {
  __builtin_amdgcn_global_load_lds(
      (const __attribute__((address_space(1))) unsigned int*)g,
      (__attribute__((address_space(3))) unsigned int*)(uintptr_t)l,
      16, 0, 0);
}

// ---------------- fp32 -> bf16 convert (X) ----------------
__global__ __launch_bounds__(256) void convertx(const float* __restrict__ X,
                                                ushort* __restrict__ Y) {
  size_t i = ((size_t)blockIdx.x * 256 + threadIdx.x) * 4;
  float4 v = *(const float4*)(X + i);
  uint2 p;
  p.x = (uint32_t)f2bf(v.x) | ((uint32_t)f2bf(v.y) << 16);
  p.y = (uint32_t)f2bf(v.z) | ((uint32_t)f2bf(v.w) << 16);
  *(uint2*)(Y + i) = p;
}

// ---------------- W (ExE fp32) -> Wt (ExE bf16, transposed) ----------------
__global__ __launch_bounds__(256) void transpose_w(const float* __restrict__ W,
                                                   ushort* __restrict__ Wt) {
  __shared__ ushort T[32][33];
  int x = threadIdx.x & 31, y = threadIdx.x >> 5;  // 32 x 8
  int c0 = blockIdx.x * 32;  // col base (n)
  int r0 = blockIdx.y * 32;  // row base (k)
#pragma unroll
  for (int i = 0; i < 4; i++) {
    int r = y + i * 8;
    T[x][r] = f2bf(W[(size_t)(r0 + r) * E_ + c0 + x]);  // coalesced read
  }
  __syncthreads();
#pragma unroll
  for (int i = 0; i < 4; i++) {
    int r = y + i * 8;
    Wt[(size_t)(c0 + r) * E_ + r0 + x] = T[r][x];  // coalesced write
  }
}

// ---------------- fused QKV GEMM: [32768,1024] x [3072,1024]^T ----------------
// Bt rows 0..1023 = Wq^T, 1024..2047 = Wk^T, 2048..3071 = Wv^T.
// Q,K written [bh][s][d]; V written TRANSPOSED [bh][d][s] (for attn B-frags).
__global__ __launch_bounds__(256) void gemm_qkv(
    const ushort* __restrict__ A, const ushort* __restrict__ Bt,
    ushort* __restrict__ Qo, ushort* __restrict__ Ko, ushort* __restrict__ Vt) {
  __shared__ __align__(16) ushort As[128 * 64];
  __shared__ __align__(16) ushort Bs[128 * 64];
  const int K = E_;
  const int tid = threadIdx.x;
  const int m0 = blockIdx.x * 128;
  const int n0 = blockIdx.y * 128;
  const int wave = tid >> 6, lane = tid & 63;
  const int wm = (wave >> 1) * 64, wn = (wave & 1) * 64;
  const int lrow = lane & 15, quad = lane >> 4;

  f4v acc[4][4];
#pragma unroll
  for (int i = 0; i < 4; i++)
#pragma unroll
    for (int j = 0; j < 4; j++) acc[i][j] = (f4v){0.f, 0.f, 0.f, 0.f};

  for (int k0 = 0; k0 < K; k0 += 64) {
    __syncthreads();
#pragma unroll
    for (int i = 0; i < 4; i++) {
      int c = i * 256 + tid;
      int r = c >> 3, cc = c & 7;
      async_cp16(A + (size_t)(m0 + r) * K + k0 + cc * 8, (void*)&As[c * 8]);
    }
#pragma unroll
    for (int i = 0; i < 4; i++) {
      int c = i * 256 + tid;
      int r = c >> 3, cc = c & 7;
      async_cp16(Bt + (size_t)(n0 + r) * K + k0 + cc * 8, (void*)&Bs[c * 8]);
    }
    __syncthreads();
#pragma unroll
    for (int kk = 0; kk < 2; kk++) {
      s8v a[4], b[4];
#pragma unroll
      for (int mi = 0; mi < 4; mi++)
        a[mi] = *(const s8v*)&As[(wm + mi * 16 + lrow) * 64 + kk * 32 + quad * 8];
#pragma unroll
      for (int ni = 0; ni < 4; ni++)
        b[ni] = *(const s8v*)&Bs[(wn + ni * 16 + lrow) * 64 + kk * 32 + quad * 8];
#pragma unroll
      for (int mi = 0; mi < 4; mi++)
#pragma unroll
        for (int ni = 0; ni < 4; ni++)
          acc[mi][ni] = __builtin_amdgcn_mfma_f32_16x16x32_bf16(a[mi], b[ni], acc[mi][ni], 0, 0, 0);
    }
  }

  // epilogue: proj uniform per block (128 | 1024)
  const int proj = n0 >> 10;           // 0=Q 1=K 2=V
  const int np0 = n0 & 1023;
  if (proj < 2) {
    ushort* C = proj == 0 ? Qo : Ko;
#pragma unroll
    for (int mi = 0; mi < 4; mi++)
#pragma unroll
      for (int ni = 0; ni < 4; ni++) {
        int n = np0 + wn + ni * 16 + lrow;
        int h = n >> 6, d = n & 63;
#pragma unroll
        for (int r = 0; r < 4; r++) {
          int m = m0 + wm + mi * 16 + quad * 4 + r;
          int bb = m >> 9, s = m & 511;
          C[(((size_t)bb * H_ + h) * S_ + s) * D_ + d] = f2bf(acc[mi][ni][r]);
        }
      }
  } else {
    // V transposed: Vt[bh][d][s]; lane's 4 regs are consecutive s -> 8B store
#pragma unroll
    for (int mi = 0; mi < 4; mi++)
#pragma unroll
      for (int ni = 0; ni < 4; ni++) {
        int n = np0 + wn + ni * 16 + lrow;
        int h = n >> 6, d = n & 63;
        int m = m0 + wm + mi * 16 + quad * 4;
        int bb = m >> 9, s = m & 511;
        ushort4 pk;
        pk.x = f2bf(acc[mi][ni][0]);
        pk.y = f2bf(acc[mi][ni][1]);
        pk.z = f2bf(acc[mi][ni][2]);
        pk.w = f2bf(acc[mi][ni][3]);
        *(ushort4*)&Vt[(((size_t)bb * H_ + h) * D_ + d) * S_ + s] = pk;
      }
  }
}

// ---------------- O GEMM: fp32 out + bias ----------------
__global__ __launch_bounds__(256) void gemm_o(
    const ushort* __restrict__ A, const ushort* __restrict__ Bt,
    float* __restrict__ C, const float* __restrict__ bias) {
  __shared__ __align__(16) ushort As[128 * 64];
  __shared__ __align__(16) ushort Bs[128 * 64];
  const int K = E_, N = E_;
  const int tid = threadIdx.x;
  const int m0 = blockIdx.x * 128;
  const int n0 = blockIdx.y * 128;
  const int wave = tid >> 6, lane = tid & 63;
  const int wm = (wave >> 1) * 64, wn = (wave & 1) * 64;
  const int lrow = lane & 15, quad = lane >> 4;

  f4v acc[4][4];
#pragma unroll
  for (int i = 0; i < 4; i++)
#pragma unroll
    for (int j = 0; j < 4; j++) acc[i][j] = (f4v){0.f, 0.f, 0.f, 0.f};

  for (int k0 = 0; k0 < K; k0 += 64) {
    __syncthreads();
#pragma unroll
    for (int i = 0; i < 4; i++) {
      int c = i * 256 + tid;
      int r = c >> 3, cc = c & 7;
      async_cp16(A + (size_t)(m0 + r) * K + k0 + cc * 8, (void*)&As[c * 8]);
    }
#pragma unroll
    for (int i = 0; i < 4; i++) {
      int c = i * 256 + tid;
      int r = c >> 3, cc = c & 7;
      async_cp16(Bt + (size_t)(n0 + r) * K + k0 + cc * 8, (void*)&Bs[c * 8]);
    }
    __syncthreads();
#pragma unroll
    for (int kk = 0; kk < 2; kk++) {
      s8v a[4], b[4];
#pragma unroll
      for (int mi = 0; mi < 4; mi++)
        a[mi] = *(const s8v*)&As[(wm + mi * 16 + lrow) * 64 + kk * 32 + quad * 8];
#pragma unroll
      for (int ni = 0; ni < 4; ni++)
        b[ni] = *(const s8v*)&Bs[(wn + ni * 16 + lrow) * 64 + kk * 32 + quad * 8];
#pragma unroll
      for (int mi = 0; mi < 4; mi++)
#pragma unroll
        for (int ni = 0; ni < 4; ni++)
          acc[mi][ni] = __builtin_amdgcn_mfma_f32_16x16x32_bf16(a[mi], b[ni], acc[mi][ni], 0, 0, 0);
    }
  }

#pragma unroll
  for (int mi = 0; mi < 4; mi++)
#pragma unroll
    for (int ni = 0; ni < 4; ni++) {
      int n = n0 + wn + ni * 16 + lrow;
      float bv = bias[n];
#pragma unroll
      for (int r = 0; r < 4; r++) {
        int m = m0 + wm + mi * 16 + quad * 4 + r;
        C[(size_t)m * N + n] = acc[mi][ni][r] + bv;
      }
    }
}

// ---------------- fused causal flash attention v2 ----------------
// grid: (S/128, B*H). block: 256 (4 waves). Wave w owns 32 q-rows (2 m-tiles).
// V comes in pre-transposed [bh][d][s]; no in-kernel transpose.
__global__ __launch_bounds__(256) void attn_kernel(
    const ushort* __restrict__ Qg, const ushort* __restrict__ Kg,
    const ushort* __restrict__ Vtg, ushort* __restrict__ AO) {
  __shared__ __align__(16) ushort Ks[64 * 64];
  __shared__ __align__(16) ushort Vts[64 * 64];   // [d][s_local]
  __shared__ __align__(16) ushort Ps[4][32 * 72]; // per-wave P / O staging (stride 72 = 144B, 16B-aligned)

  const int qb2 = blockIdx.x;           // 0..3 (128 q rows per block)
  const int bh = blockIdx.y;            // 0..1023
  const int b = bh >> 4, h = bh & 15;
  const int tid = threadIdx.x, wave = tid >> 6, lane = tid & 63;
  const int lrow = lane & 15, quad = lane >> 4;
  const size_t base = (size_t)bh * (S_ * D_);
  const int wq0 = qb2 * 128 + wave * 32;  // wave's first q row

  // Q fragments straight from global (rows hit L1 across quad/kk within the wave)
  s8v qf[2][2];
#pragma unroll
  for (int mi = 0; mi < 2; mi++)
#pragma unroll
    for (int kk = 0; kk < 2; kk++)
      qf[mi][kk] = *(const s8v*)(Qg + base + (size_t)(wq0 + mi * 16 + lrow) * 64 +
                                 kk * 32 + quad * 8);

  f4v o[2][4];
#pragma unroll
  for (int mi = 0; mi < 2; mi++)
#pragma unroll
    for (int di = 0; di < 4; di++) o[mi][di] = (f4v){0.f, 0.f, 0.f, 0.f};
  float mr[2][4], lr[2][4];
#pragma unroll
  for (int mi = 0; mi < 2; mi++)
#pragma unroll
    for (int r = 0; r < 4; r++) { mr[mi][r] = -INFINITY; lr[mi][r] = 0.f; }

  ushort* pw = &Ps[wave][0];
  const int ktmax = qb2 * 2 + 1;

  for (int kt = 0; kt <= ktmax; kt++) {
    __syncthreads();  // all waves done reading previous Ks/Vts
    // stage K tile [s][d] and Vt tile [d][s] via async global->LDS
#pragma unroll
    for (int i = 0; i < 2; i++) {
      int c = i * 256 + tid;
      int r = c >> 3, cc = c & 7;
      async_cp16(Kg + base + (size_t)(kt * 64 + r) * 64 + cc * 8, (void*)&Ks[c * 8]);
    }
#pragma unroll
    for (int i = 0; i < 2; i++) {
      int c = i * 256 + tid;
      int d = c >> 3, cc = c & 7;
      async_cp16(Vtg + base + (size_t)d * S_ + kt * 64 + cc * 8, (void*)&Vts[c * 8]);
    }
    __syncthreads();

    if (kt * 64 <= wq0 + 31) {  // wave-uniform: skip fully-masked tiles
      // scores: 32 q-rows x 64 k-cols per wave
      f4v sc[2][4];
#pragma unroll
      for (int mi = 0; mi < 2; mi++)
#pragma unroll
        for (int ni = 0; ni < 4; ni++) sc[mi][ni] = (f4v){0.f, 0.f, 0.f, 0.f};
#pragma unroll
      for (int kk = 0; kk < 2; kk++)
#pragma unroll
        for (int ni = 0; ni < 4; ni++) {
          s8v kf = *(const s8v*)&Ks[(ni * 16 + lrow) * 64 + kk * 32 + quad * 8];
#pragma unroll
          for (int mi = 0; mi < 2; mi++)
            sc[mi][ni] = __builtin_amdgcn_mfma_f32_16x16x32_bf16(qf[mi][kk], kf, sc[mi][ni], 0, 0, 0);
        }

      // causal mask (only tiles straddling the diagonal)
      if (kt * 64 + 63 > wq0) {
#pragma unroll
        for (int mi = 0; mi < 2; mi++)
#pragma unroll
          for (int ni = 0; ni < 4; ni++) {
            int kcol = kt * 64 + ni * 16 + lrow;
            int qrow0 = wq0 + mi * 16 + quad * 4;
#pragma unroll
            for (int r = 0; r < 4; r++)
              if (kcol > qrow0 + r) sc[mi][ni][r] = -INFINITY;
          }
      }

      // online softmax per m-tile; write P to per-wave LDS (C-layout -> row-major)
#pragma unroll
      for (int mi = 0; mi < 2; mi++) {
        float bm[4];
#pragma unroll
        for (int r = 0; r < 4; r++)
          bm[r] = fmaxf(fmaxf(sc[mi][0][r], sc[mi][1][r]), fmaxf(sc[mi][2][r], sc[mi][3][r]));
#pragma unroll
        for (int off = 1; off < 16; off <<= 1)
#pragma unroll
          for (int r = 0; r < 4; r++) bm[r] = fmaxf(bm[r], __shfl_xor(bm[r], off));
        float al[4];
#pragma unroll
        for (int r = 0; r < 4; r++) {
          float mn = fmaxf(mr[mi][r], bm[r]);
          al[r] = __expf(mr[mi][r] - mn);
          mr[mi][r] = mn;
        }
        float bs[4] = {0.f, 0.f, 0.f, 0.f};
#pragma unroll
        for (int ni = 0; ni < 4; ni++)
#pragma unroll
          for (int r = 0; r < 4; r++) {
            float p = __expf(sc[mi][ni][r] - mr[mi][r]);
            pw[(mi * 16 + quad * 4 + r) * 72 + ni * 16 + lrow] = f2bf(p);
            bs[r] += p;
          }
#pragma unroll
        for (int off = 1; off < 16; off <<= 1)
#pragma unroll
          for (int r = 0; r < 4; r++) bs[r] += __shfl_xor(bs[r], off);
#pragma unroll
        for (int r = 0; r < 4; r++) lr[mi][r] = lr[mi][r] * al[r] + bs[r];
#pragma unroll
        for (int di = 0; di < 4; di++)
#pragma unroll
          for (int r = 0; r < 4; r++) o[mi][di][r] *= al[r];
      }

      // PV: P as A-frag (LDS roundtrip, wave-local), Vt as B-frag
#pragma unroll
      for (int kk = 0; kk < 2; kk++) {
        s8v pf0 = *(const s8v*)&pw[lrow * 72 + kk * 32 + quad * 8];
        s8v pf1 = *(const s8v*)&pw[(16 + lrow) * 72 + kk * 32 + quad * 8];
#pragma unroll
        for (int di = 0; di < 4; di++) {
          s8v vf = *(const s8v*)&Vts[(di * 16 + lrow) * 64 + kk * 32 + quad * 8];
          o[0][di] = __builtin_amdgcn_mfma_f32_16x16x32_bf16(pf0, vf, o[0][di], 0, 0, 0);
          o[1][di] = __builtin_amdgcn_mfma_f32_16x16x32_bf16(pf1, vf, o[1][di], 0, 0, 0);
        }
      }
    }
  }

  // normalize, stage to LDS, coalesced 16B merged-head stores
  float inv[2][4];
#pragma unroll
  for (int mi = 0; mi < 2; mi++)
#pragma unroll
    for (int r = 0; r < 4; r++) inv[mi][r] = 1.0f / lr[mi][r];
#pragma unroll
  for (int mi = 0; mi < 2; mi++)
#pragma unroll
    for (int di = 0; di < 4; di++)
#pragma unroll
      for (int r = 0; r < 4; r++)
        pw[(mi * 16 + quad * 4 + r) * 72 + di * 16 + lrow] = f2bf(o[mi][di][r] * inv[mi][r]);

#pragma unroll
  for (int i = 0; i < 4; i++) {
    int c = i * 64 + lane;
    int row = c >> 3, cc = c & 7;
    uint4 val = *(const uint4*)&pw[row * 72 + cc * 8];
    int q = qb2 * 128 + wave * 32 + row;
    size_t off = ((size_t)b * S_ + q) * E_ + h * 64 + cc * 8;
    *(uint4*)&AO[off] = val;
  }
}

// ---------------- launch ----------------
extern "C" void kernel_launch(void* const* d_in, const int* in_sizes, int n_in,
                              void* d_out, int out_size, void* d_ws, size_t ws_size,
                              hipStream_t stream) {
  const float* X = (const float*)d_in[0];
  const float* Wq = (const float*)d_in[1];
  const float* Wk = (const float*)d_in[2];
  const float* Wv = (const float*)d_in[3];
  const float* Wo = (const float*)d_in[4];
  const float* bo = (const float*)d_in[5];
  float* out = (float*)d_out;

  // ws layout (bytes). AO aliases Xb (Xb dead after QKV GEMM). Total ~277 MB.
  char* ws = (char*)d_ws;
  ushort* Xb = (ushort*)(ws);                      //  67,108,864
  ushort* Wqkvt = (ushort*)(ws + 67108864);        //   6,291,456 (Wq^T|Wk^T|Wv^T)
  ushort* Wot = (ushort*)(ws + 73400320);          //   2,097,152
  ushort* Qb = (ushort*)(ws + 75497472);           //  67,108,864
  ushort* Kb = (ushort*)(ws + 142606336);          //  67,108,864
  ushort* Vtb = (ushort*)(ws + 209715200);         //  67,108,864 ([bh][d][s])
  ushort* AO = Xb;

  convertx<<<32768, 256, 0, stream>>>(X, Xb);
  transpose_w<<<dim3(32, 32), 256, 0, stream>>>(Wq, Wqkvt);
  transpose_w<<<dim3(32, 32), 256, 0, stream>>>(Wk, Wqkvt + 1024 * 1024);
  transpose_w<<<dim3(32, 32), 256, 0, stream>>>(Wv, Wqkvt + 2 * 1024 * 1024);
  transpose_w<<<dim3(32, 32), 256, 0, stream>>>(Wo, Wot);

  gemm_qkv<<<dim3(256, 24), 256, 0, stream>>>(Xb, Wqkvt, Qb, Kb, Vtb);

  attn_kernel<<<dim3(4, 1024), 256, 0, stream>>>(Qb, Kb, Vtb, AO);

  gemm_o<<<dim3(256, 8), 256, 0, stream>>>(AO, Wot, out, bo);
}

// Round 3
// 821.653 us; speedup vs baseline: 1.2945x; 1.1294x over previous
//
#include <hip/hip_runtime.h>
#include <hip/hip_bf16.h>
#include <cstdint>
#include <cstddef>

// Problem constants
#define B_ 64
#define S_ 512
#define E_ 1024
#define H_ 16
#define D_ 64

typedef __attribute__((ext_vector_type(8))) short s8v;   // 8 bf16 = 4 VGPRs (A/B frag)
typedef __attribute__((ext_vector_type(4))) float f4v;   // C/D frag

__device__ __forceinline__ ushort f2bf(float f) {
  uint32_t u = __builtin_bit_cast(uint32_t, f);
  u += 0x7fffu + ((u >> 16) & 1u);   // RNE
  return (ushort)(u >> 16);
}

// async global->LDS, 16B per lane. LDS dest must be wave-uniform base + lane*16.
__device__ __forceinline__ void async_cp16(const void* g, void* l) {
  __builtin_amdgcn_global_load_lds(
      (const __attribute__((address_space(1))) unsigned int*)g,
      (__attribute__((address_space(3))) unsigned int*)(uintptr_t)l,
      16, 0, 0);
}

// LDS tile swizzle: row r (128B = 8 chunks of 16B) stores global chunk c at
// slot c^(r&7). Fragment read of chunk j for row r -> slot j^(r&7).
// 16-lane groups then spread all 32 banks at the 8-word b128 minimum.

// ---------------- fp32 -> bf16 convert (X) ----------------
__global__ __launch_bounds__(256) void convertx(const float* __restrict__ X,
                                                ushort* __restrict__ Y) {
  size_t i = ((size_t)blockIdx.x * 256 + threadIdx.x) * 4;
  float4 v = *(const float4*)(X + i);
  uint2 p;
  p.x = (uint32_t)f2bf(v.x) | ((uint32_t)f2bf(v.y) << 16);
  p.y = (uint32_t)f2bf(v.z) | ((uint32_t)f2bf(v.w) << 16);
  *(uint2*)(Y + i) = p;
}

// ---------------- W (ExE fp32) -> Wt (ExE bf16, transposed) ----------------
__global__ __launch_bounds__(256) void transpose_w(const float* __restrict__ W,
                                                   ushort* __restrict__ Wt) {
  __shared__ ushort T[32][33];
  int x = threadIdx.x & 31, y = threadIdx.x >> 5;  // 32 x 8
  int c0 = blockIdx.x * 32;  // col base (n)
  int r0 = blockIdx.y * 32;  // row base (k)
#pragma unroll
  for (int i = 0; i < 4; i++) {
    int r = y + i * 8;
    T[x][r] = f2bf(W[(size_t)(r0 + r) * E_ + c0 + x]);  // coalesced read
  }
  __syncthreads();
#pragma unroll
  for (int i = 0; i < 4; i++) {
    int r = y + i * 8;
    Wt[(size_t)(c0 + r) * E_ + r0 + x] = T[r][x];  // coalesced write
  }
}

// ---------------- fused QKV GEMM: [32768,1024] x [3072,1024]^T ----------------
// Bt rows 0..1023 = Wq^T, 1024..2047 = Wk^T, 2048..3071 = Wv^T.
// grid (24, 256): n-tile fastest so consecutive blocks reuse the A panel in L2.
// Q,K written [bh][s][d]; V written TRANSPOSED [bh][d][s].
__global__ __launch_bounds__(256) void gemm_qkv(
    const ushort* __restrict__ A, const ushort* __restrict__ Bt,
    ushort* __restrict__ Qo, ushort* __restrict__ Ko, ushort* __restrict__ Vt) {
  __shared__ __align__(16) ushort smem[17408];  // As(8192) + Bs(8192); epilogue reuses all
  ushort* As = smem;
  ushort* Bs = smem + 8192;
  const int K = E_;
  const int tid = threadIdx.x;
  const int n0 = blockIdx.x * 128;
  const int m0 = blockIdx.y * 128;
  const int wave = tid >> 6, lane = tid & 63;
  const int wm = (wave >> 1) * 64, wn = (wave & 1) * 64;
  const int lrow = lane & 15, quad = lane >> 4;
  const int swl = lrow & 7;

  f4v acc[4][4];
#pragma unroll
  for (int i = 0; i < 4; i++)
#pragma unroll
    for (int j = 0; j < 4; j++) acc[i][j] = (f4v){0.f, 0.f, 0.f, 0.f};

  for (int k0 = 0; k0 < K; k0 += 64) {
    __syncthreads();
#pragma unroll
    for (int i = 0; i < 4; i++) {
      int c = i * 256 + tid;
      int r = c >> 3, cc = c & 7;
      int sc = cc ^ (r & 7);
      async_cp16(A + (size_t)(m0 + r) * K + k0 + sc * 8, (void*)&As[c * 8]);
    }
#pragma unroll
    for (int i = 0; i < 4; i++) {
      int c = i * 256 + tid;
      int r = c >> 3, cc = c & 7;
      int sc = cc ^ (r & 7);
      async_cp16(Bt + (size_t)(n0 + r) * K + k0 + sc * 8, (void*)&Bs[c * 8]);
    }
    __syncthreads();
#pragma unroll
    for (int kk = 0; kk < 2; kk++) {
      const int ch = (kk * 4 + quad) ^ swl;
      s8v a[4], b[4];
#pragma unroll
      for (int mi = 0; mi < 4; mi++)
        a[mi] = *(const s8v*)&As[(wm + mi * 16 + lrow) * 64 + ch * 8];
#pragma unroll
      for (int ni = 0; ni < 4; ni++)
        b[ni] = *(const s8v*)&Bs[(wn + ni * 16 + lrow) * 64 + ch * 8];
#pragma unroll
      for (int mi = 0; mi < 4; mi++)
#pragma unroll
        for (int ni = 0; ni < 4; ni++)
          acc[mi][ni] = __builtin_amdgcn_mfma_f32_16x16x32_bf16(a[mi], b[ni], acc[mi][ni], 0, 0, 0);
    }
  }

  __syncthreads();  // fragment reads done; smem is reusable
  const int proj = n0 >> 10;           // 0=Q 1=K 2=V (uniform per block)
  const int np0 = n0 & 1023;
  const int bb = m0 >> 9, s0 = m0 & 511;

  if (proj < 2) {
    // stage tile [m][n] row-major, stride 136 (pad); then 16B coalesced stores
#pragma unroll
    for (int mi = 0; mi < 4; mi++)
#pragma unroll
      for (int ni = 0; ni < 4; ni++)
#pragma unroll
        for (int r = 0; r < 4; r++)
          smem[(wm + mi * 16 + quad * 4 + r) * 136 + wn + ni * 16 + lrow] =
              f2bf(acc[mi][ni][r]);
    __syncthreads();
    ushort* C = proj == 0 ? Qo : Ko;
    const int half = tid >> 7, tl = tid & 127;
    const int h = (np0 >> 6) + half;
    const size_t gbase = (((size_t)bb * H_ + h) * S_ + s0) * D_;  // 16KB contiguous region
#pragma unroll
    for (int it = 0; it < 8; it++) {
      int o = it * 2048 + tl * 16;        // byte offset in region
      int srow = o >> 7, inner = o & 127;
      uint4 v = *(const uint4*)((const char*)smem + srow * 272 + half * 128 + inner);
      *(uint4*)&C[gbase + (o >> 1)] = v;
    }
  } else {
    // V transposed: stage [n][m] stride 136 via 8B packed writes, then 16B stores
#pragma unroll
    for (int mi = 0; mi < 4; mi++)
#pragma unroll
      for (int ni = 0; ni < 4; ni++) {
        ushort4 pk;
        pk.x = f2bf(acc[mi][ni][0]);
        pk.y = f2bf(acc[mi][ni][1]);
        pk.z = f2bf(acc[mi][ni][2]);
        pk.w = f2bf(acc[mi][ni][3]);
        *(ushort4*)&smem[(wn + ni * 16 + lrow) * 136 + wm + mi * 16 + quad * 4] = pk;
      }
    __syncthreads();
    const int drow = tid >> 1, halfm = tid & 1;
    const int h = (np0 >> 6) + (drow >> 6), d = drow & 63;
    const size_t gbase = (((size_t)bb * H_ + h) * D_ + d) * S_ + s0 + halfm * 64;
#pragma unroll
    for (int j = 0; j < 8; j++) {
      uint4 v = *(const uint4*)((const char*)smem + drow * 272 + halfm * 128 + j * 16);
      *(uint4*)&Vt[gbase + j * 8] = v;
    }
  }
}

// ---------------- O GEMM: fp32 out + bias ----------------
// grid (8, 256): n-tile fastest.
__global__ __launch_bounds__(256) void gemm_o(
    const ushort* __restrict__ A, const ushort* __restrict__ Bt,
    float* __restrict__ C, const float* __restrict__ bias) {
  __shared__ __align__(16) ushort As[128 * 64];
  __shared__ __align__(16) ushort Bs[128 * 64];
  const int K = E_, N = E_;
  const int tid = threadIdx.x;
  const int n0 = blockIdx.x * 128;
  const int m0 = blockIdx.y * 128;
  const int wave = tid >> 6, lane = tid & 63;
  const int wm = (wave >> 1) * 64, wn = (wave & 1) * 64;
  const int lrow = lane & 15, quad = lane >> 4;
  const int swl = lrow & 7;

  f4v acc[4][4];
#pragma unroll
  for (int i = 0; i < 4; i++)
#pragma unroll
    for (int j = 0; j < 4; j++) acc[i][j] = (f4v){0.f, 0.f, 0.f, 0.f};

  for (int k0 = 0; k0 < K; k0 += 64) {
    __syncthreads();
#pragma unroll
    for (int i = 0; i < 4; i++) {
      int c = i * 256 + tid;
      int r = c >> 3, cc = c & 7;
      int sc = cc ^ (r & 7);
      async_cp16(A + (size_t)(m0 + r) * K + k0 + sc * 8, (void*)&As[c * 8]);
    }
#pragma unroll
    for (int i = 0; i < 4; i++) {
      int c = i * 256 + tid;
      int r = c >> 3, cc = c & 7;
      int sc = cc ^ (r & 7);
      async_cp16(Bt + (size_t)(n0 + r) * K + k0 + sc * 8, (void*)&Bs[c * 8]);
    }
    __syncthreads();
#pragma unroll
    for (int kk = 0; kk < 2; kk++) {
      const int ch = (kk * 4 + quad) ^ swl;
      s8v a[4], b[4];
#pragma unroll
      for (int mi = 0; mi < 4; mi++)
        a[mi] = *(const s8v*)&As[(wm + mi * 16 + lrow) * 64 + ch * 8];
#pragma unroll
      for (int ni = 0; ni < 4; ni++)
        b[ni] = *(const s8v*)&Bs[(wn + ni * 16 + lrow) * 64 + ch * 8];
#pragma unroll
      for (int mi = 0; mi < 4; mi++)
#pragma unroll
        for (int ni = 0; ni < 4; ni++)
          acc[mi][ni] = __builtin_amdgcn_mfma_f32_16x16x32_bf16(a[mi], b[ni], acc[mi][ni], 0, 0, 0);
    }
  }

#pragma unroll
  for (int mi = 0; mi < 4; mi++)
#pragma unroll
    for (int ni = 0; ni < 4; ni++) {
      int n = n0 + wn + ni * 16 + lrow;
      float bv = bias[n];
#pragma unroll
      for (int r = 0; r < 4; r++) {
        int m = m0 + wm + mi * 16 + quad * 4 + r;
        C[(size_t)m * N + n] = acc[mi][ni][r] + bv;
      }
    }
}

// ---------------- fused causal flash attention v2 + swizzled staging ----------------
// grid: (S/128, B*H). block: 256 (4 waves). Wave w owns 32 q-rows (2 m-tiles).
// V comes in pre-transposed [bh][d][s]; no in-kernel transpose.
__global__ __launch_bounds__(256) void attn_kernel(
    const ushort* __restrict__ Qg, const ushort* __restrict__ Kg,
    const ushort* __restrict__ Vtg, ushort* __restrict__ AO) {
  __shared__ __align__(16) ushort Ks[64 * 64];
  __shared__ __align__(16) ushort Vts[64 * 64];   // [d][s_local]
  __shared__ __align__(16) ushort Ps[4][32 * 72]; // per-wave P / O staging

  const int qb2 = blockIdx.x;           // 0..3 (128 q rows per block)
  const int bh = blockIdx.y;            // 0..1023
  const int b = bh >> 4, h = bh & 15;
  const int tid = threadIdx.x, wave = tid >> 6, lane = tid & 63;
  const int lrow = lane & 15, quad = lane >> 4;
  const int swl = lrow & 7;
  const size_t base = (size_t)bh * (S_ * D_);
  const int wq0 = qb2 * 128 + wave * 32;  // wave's first q row

  // Q fragments straight from global
  s8v qf[2][2];
#pragma unroll
  for (int mi = 0; mi < 2; mi++)
#pragma unroll
    for (int kk = 0; kk < 2; kk++)
      qf[mi][kk] = *(const s8v*)(Qg + base + (size_t)(wq0 + mi * 16 + lrow) * 64 +
                                 kk * 32 + quad * 8);

  f4v o[2][4];
#pragma unroll
  for (int mi = 0; mi < 2; mi++)
#pragma unroll
    for (int di = 0; di < 4; di++) o[mi][di] = (f4v){0.f, 0.f, 0.f, 0.f};
  float mr[2][4], lr[2][4];
#pragma unroll
  for (int mi = 0; mi < 2; mi++)
#pragma unroll
    for (int r = 0; r < 4; r++) { mr[mi][r] = -INFINITY; lr[mi][r] = 0.f; }

  ushort* pw = &Ps[wave][0];
  const int ktmax = qb2 * 2 + 1;

  for (int kt = 0; kt <= ktmax; kt++) {
    __syncthreads();  // all waves done reading previous Ks/Vts
    // stage K tile [s][d] and Vt tile [d][s], swizzled
#pragma unroll
    for (int i = 0; i < 2; i++) {
      int c = i * 256 + tid;
      int r = c >> 3, cc = c & 7;
      int sc = cc ^ (r & 7);
      async_cp16(Kg + base + (size_t)(kt * 64 + r) * 64 + sc * 8, (void*)&Ks[c * 8]);
    }
#pragma unroll
    for (int i = 0; i < 2; i++) {
      int c = i * 256 + tid;
      int d = c >> 3, cc = c & 7;
      int sc = cc ^ (d & 7);
      async_cp16(Vtg + base + (size_t)d * S_ + kt * 64 + sc * 8, (void*)&Vts[c * 8]);
    }
    __syncthreads();

    if (kt * 64 <= wq0 + 31) {  // wave-uniform: skip fully-masked tiles
      f4v sc[2][4];
#pragma unroll
      for (int mi = 0; mi < 2; mi++)
#pragma unroll
        for (int ni = 0; ni < 4; ni++) sc[mi][ni] = (f4v){0.f, 0.f, 0.f, 0.f};
#pragma unroll
      for (int kk = 0; kk < 2; kk++) {
        const int ch = (kk * 4 + quad) ^ swl;
#pragma unroll
        for (int ni = 0; ni < 4; ni++) {
          s8v kf = *(const s8v*)&Ks[(ni * 16 + lrow) * 64 + ch * 8];
#pragma unroll
          for (int mi = 0; mi < 2; mi++)
            sc[mi][ni] = __builtin_amdgcn_mfma_f32_16x16x32_bf16(qf[mi][kk], kf, sc[mi][ni], 0, 0, 0);
        }
      }

      // causal mask (only tiles straddling the diagonal)
      if (kt * 64 + 63 > wq0) {
#pragma unroll
        for (int mi = 0; mi < 2; mi++)
#pragma unroll
          for (int ni = 0; ni < 4; ni++) {
            int kcol = kt * 64 + ni * 16 + lrow;
            int qrow0 = wq0 + mi * 16 + quad * 4;
#pragma unroll
            for (int r = 0; r < 4; r++)
              if (kcol > qrow0 + r) sc[mi][ni][r] = -INFINITY;
          }
      }

      // online softmax per m-tile; write P to per-wave LDS (C-layout -> row-major)
#pragma unroll
      for (int mi = 0; mi < 2; mi++) {
        float bm[4];
#pragma unroll
        for (int r = 0; r < 4; r++)
          bm[r] = fmaxf(fmaxf(sc[mi][0][r], sc[mi][1][r]), fmaxf(sc[mi][2][r], sc[mi][3][r]));
#pragma unroll
        for (int off = 1; off < 16; off <<= 1)
#pragma unroll
          for (int r = 0; r < 4; r++) bm[r] = fmaxf(bm[r], __shfl_xor(bm[r], off));
        float al[4];
#pragma unroll
        for (int r = 0; r < 4; r++) {
          float mn = fmaxf(mr[mi][r], bm[r]);
          al[r] = __expf(mr[mi][r] - mn);
          mr[mi][r] = mn;
        }
        float bs[4] = {0.f, 0.f, 0.f, 0.f};
#pragma unroll
        for (int ni = 0; ni < 4; ni++)
#pragma unroll
          for (int r = 0; r < 4; r++) {
            float p = __expf(sc[mi][ni][r] - mr[mi][r]);
            pw[(mi * 16 + quad * 4 + r) * 72 + ni * 16 + lrow] = f2bf(p);
            bs[r] += p;
          }
#pragma unroll
        for (int off = 1; off < 16; off <<= 1)
#pragma unroll
          for (int r = 0; r < 4; r++) bs[r] += __shfl_xor(bs[r], off);
#pragma unroll
        for (int r = 0; r < 4; r++) lr[mi][r] = lr[mi][r] * al[r] + bs[r];
#pragma unroll
        for (int di = 0; di < 4; di++)
#pragma unroll
          for (int r = 0; r < 4; r++) o[mi][di][r] *= al[r];
      }

      // PV: P as A-frag (wave-local LDS roundtrip), Vt as B-frag (swizzled)
#pragma unroll
      for (int kk = 0; kk < 2; kk++) {
        const int ch = (kk * 4 + quad) ^ swl;
        s8v pf0 = *(const s8v*)&pw[lrow * 72 + kk * 32 + quad * 8];
        s8v pf1 = *(const s8v*)&pw[(16 + lrow) * 72 + kk * 32 + quad * 8];
#pragma unroll
        for (int di = 0; di < 4; di++) {
          s8v vf = *(const s8v*)&Vts[(di * 16 + lrow) * 64 + ch * 8];
          o[0][di] = __builtin_amdgcn_mfma_f32_16x16x32_bf16(pf0, vf, o[0][di], 0, 0, 0);
          o[1][di] = __builtin_amdgcn_mfma_f32_16x16x32_bf16(pf1, vf, o[1][di], 0, 0, 0);
        }
      }
    }
  }

  // normalize, stage to LDS, coalesced 16B merged-head stores
  float inv[2][4];
#pragma unroll
  for (int mi = 0; mi < 2; mi++)
#pragma unroll
    for (int r = 0; r < 4; r++) inv[mi][r] = 1.0f / lr[mi][r];
#pragma unroll
  for (int mi = 0; mi < 2; mi++)
#pragma unroll
    for (int di = 0; di < 4; di++)
#pragma unroll
      for (int r = 0; r < 4; r++)
        pw[(mi * 16 + quad * 4 + r) * 72 + di * 16 + lrow] = f2bf(o[mi][di][r] * inv[mi][r]);

#pragma unroll
  for (int i = 0; i < 4; i++) {
    int c = i * 64 + lane;
    int row = c >> 3, cc = c & 7;
    uint4 val = *(const uint4*)&pw[row * 72 + cc * 8];
    int q = qb2 * 128 + wave * 32 + row;
    size_t off = ((size_t)b * S_ + q) * E_ + h * 64 + cc * 8;
    *(uint4*)&AO[off] = val;
  }
}

// ---------------- launch ----------------
extern "C" void kernel_launch(void* const* d_in, const int* in_sizes, int n_in,
                              void* d_out, int out_size, void* d_ws, size_t ws_size,
                              hipStream_t stream) {
  const float* X = (const float*)d_in[0];
  const float* Wq = (const float*)d_in[1];
  const float* Wk = (const float*)d_in[2];
  const float* Wv = (const float*)d_in[3];
  const float* Wo = (const float*)d_in[4];
  const float* bo = (const float*)d_in[5];
  float* out = (float*)d_out;

  // ws layout (bytes). AO aliases Xb (Xb dead after QKV GEMM). Total ~277 MB.
  char* ws = (char*)d_ws;
  ushort* Xb = (ushort*)(ws);                      //  67,108,864
  ushort* Wqkvt = (ushort*)(ws + 67108864);        //   6,291,456 (Wq^T|Wk^T|Wv^T)
  ushort* Wot = (ushort*)(ws + 73400320);          //   2,097,152
  ushort* Qb = (ushort*)(ws + 75497472);           //  67,108,864
  ushort* Kb = (ushort*)(ws + 142606336);          //  67,108,864
  ushort* Vtb = (ushort*)(ws + 209715200);         //  67,108,864 ([bh][d][s])
  ushort* AO = Xb;

  convertx<<<32768, 256, 0, stream>>>(X, Xb);
  transpose_w<<<dim3(32, 32), 256, 0, stream>>>(Wq, Wqkvt);
  transpose_w<<<dim3(32, 32), 256, 0, stream>>>(Wk, Wqkvt + 1024 * 1024);
  transpose_w<<<dim3(32, 32), 256, 0, stream>>>(Wv, Wqkvt + 2 * 1024 * 1024);
  transpose_w<<<dim3(32, 32), 256, 0, stream>>>(Wo, Wot);

  gemm_qkv<<<dim3(24, 256), 256, 0, stream>>>(Xb, Wqkvt, Qb, Kb, Vtb);

  attn_kernel<<<dim3(4, 1024), 256, 0, stream>>>(Qb, Kb, Vtb, AO);

  gemm_o<<<dim3(8, 256), 256, 0, stream>>>(AO, Wot, out, bo);
}